// Round 3
// baseline (776.918 us; speedup 1.0000x reference)
//
#include <hip/hip_runtime.h>
#include <hip/hip_bf16.h>
#include <stdint.h>

typedef __hip_bfloat16 bf16;
typedef __attribute__((ext_vector_type(8))) __bf16 bf16x8;
typedef __attribute__((ext_vector_type(8))) unsigned short ushort8;
typedef __attribute__((ext_vector_type(4))) float floatx4;

#define MFMA_16x16x32(a, b, c) __builtin_amdgcn_mfma_f32_16x16x32_bf16((a), (b), (c), 0, 0, 0)

// async global->LDS, 16B per lane. LDS dest = wave-uniform base + lane*16.
// Global side is per-lane addressed -> we swizzle the SOURCE chunk.
__device__ __forceinline__ void async_load16(const bf16* g, bf16* l) {
  __builtin_amdgcn_global_load_lds(
      (const __attribute__((address_space(1))) unsigned int*)g,
      (__attribute__((address_space(3))) unsigned int*)l,
      16, 0, 0);
}

// ---------------------------------------------------------------------------
// fp32 -> bf16 cast, 8 elems/thread
// ---------------------------------------------------------------------------
__global__ __launch_bounds__(256)
void f32_to_bf16_k(const float* __restrict__ in, bf16* __restrict__ out, int n)
{
  const int i = (blockIdx.x * 256 + threadIdx.x) * 8;
  if (i >= n) return;
  bf16 tmp[8];
#pragma unroll
  for (int j = 0; j < 8; ++j) tmp[j] = __float2bfloat16(in[i + j]);
  *(ushort8*)&out[i] = *(const ushort8*)tmp;
}

// ---------------------------------------------------------------------------
// C[M,N] = A[M,K] @ B[N,K]^T   (bf16 in, fp32 acc, bf16 or fp32 out)
// m97 structure + XOR chunk swizzle (2-way conflicts only)
// ---------------------------------------------------------------------------
__global__ __launch_bounds__(256, 2)
void gemm_bt(const bf16* __restrict__ A, const bf16* __restrict__ B,
             bf16* __restrict__ Cb, float* __restrict__ Cf,
             int M, int N, int K)
{
  __shared__ bf16 sA[128 * 32];
  __shared__ bf16 sB[128 * 32];

  const int tid  = threadIdx.x;
  const int lane = tid & 63;
  const int w    = tid >> 6;
  const int wm   = w >> 1;
  const int wn   = w & 1;
  const int quad = lane >> 4;
  const int l16  = lane & 15;
  const int tileM = blockIdx.y * 128;
  const int tileN = blockIdx.x * 128;
  const int rmask = (l16 & 3) ^ ((l16 >> 2) & 3);

  floatx4 acc[4][4];
#pragma unroll
  for (int i = 0; i < 4; ++i)
#pragma unroll
    for (int j = 0; j < 4; ++j) acc[i][j] = (floatx4){0.f, 0.f, 0.f, 0.f};

  int st_row[2], st_col[2];
#pragma unroll
  for (int s = 0; s < 2; ++s) {
    const int cid = (w * 2 + s) * 64 + lane;
    const int row = cid >> 2;
    st_row[s] = row;
    st_col[s] = ((cid & 3) ^ ((row & 3) ^ ((row >> 2) & 3))) << 3;
  }

  for (int k0 = 0; k0 < K; k0 += 32) {
    __syncthreads();
#pragma unroll
    for (int s = 0; s < 2; ++s) {
      async_load16(A + (size_t)(tileM + st_row[s]) * K + k0 + st_col[s], &sA[(w * 2 + s) * 64 * 8]);
      async_load16(B + (size_t)(tileN + st_row[s]) * K + k0 + st_col[s], &sB[(w * 2 + s) * 64 * 8]);
    }
    __syncthreads();

    bf16x8 af[4], bfr[4];
#pragma unroll
    for (int i = 0; i < 4; ++i)
      af[i] = *(const bf16x8*)&sA[(wm * 64 + i * 16 + l16) * 32 + (quad ^ rmask) * 8];
#pragma unroll
    for (int j = 0; j < 4; ++j)
      bfr[j] = *(const bf16x8*)&sB[(wn * 64 + j * 16 + l16) * 32 + (quad ^ rmask) * 8];
#pragma unroll
    for (int i = 0; i < 4; ++i)
#pragma unroll
      for (int j = 0; j < 4; ++j)
        acc[i][j] = MFMA_16x16x32(af[i], bfr[j], acc[i][j]);
  }

#pragma unroll
  for (int i = 0; i < 4; ++i)
#pragma unroll
    for (int j = 0; j < 4; ++j)
#pragma unroll
      for (int r = 0; r < 4; ++r) {
        const int row = tileM + wm * 64 + i * 16 + quad * 4 + r;
        const int col = tileN + wn * 64 + j * 16 + l16;
        if (Cf) Cf[(size_t)row * N + col] = acc[i][j][r];
        else    Cb[(size_t)row * N + col] = __float2bfloat16(acc[i][j][r]);
      }
}

// ---------------------------------------------------------------------------
// V transpose: qkv[b*T+t, 4096 + h*128 + dim] -> Vt[(bh*128 + dim)*2048 + t]
// ---------------------------------------------------------------------------
__global__ __launch_bounds__(256)
void transpose_v(const bf16* __restrict__ qkv, bf16* __restrict__ Vt)
{
  __shared__ bf16 tile[64 * 128];
  const int t0 = blockIdx.x * 64;
  const int bh = blockIdx.y;
  const int b = bh >> 4;
  const int h = bh & 15;
  const int tid = threadIdx.x;
  const bf16* src = qkv + (size_t)(b * 2048 + t0) * 6144 + 4096 + h * 128;
#pragma unroll
  for (int s = 0; s < 4; ++s) {
    const int cid = s * 256 + tid;
    const int row = cid >> 4;
    const int col = (cid & 15) << 3;
    *(ushort8*)&tile[row * 128 + col] = *(const ushort8*)&src[(size_t)row * 6144 + col];
  }
  __syncthreads();
  const int dim = tid >> 1;
  const int tp  = (tid & 1) << 5;
  bf16 vals[32];
#pragma unroll
  for (int t = 0; t < 32; ++t) vals[t] = tile[(tp + t) * 128 + dim];
  bf16* dst = Vt + (size_t)(bh * 128 + dim) * 2048 + t0 + tp;
#pragma unroll
  for (int s = 0; s < 4; ++s) *(ushort8*)&dst[s * 8] = ((const ushort8*)vals)[s];
}

// ---------------------------------------------------------------------------
// Flash attention, causal. BQ=128: one block per (q-tile of 128, b*h).
// 4 waves; wave w owns q-rows w*32..w*32+31 (2 m-subtiles of 16).
// Q lives in registers (staged once via LDS). K/V tiles of 64 keys per iter.
// All LDS XOR-chunk-swizzled (2-way conflicts only).
// ---------------------------------------------------------------------------
__global__ __launch_bounds__(256, 2)
void flash_attn(const bf16* __restrict__ qkv, const bf16* __restrict__ Vt,
                bf16* __restrict__ outb)
{
  // sK [64 keys][128 d] | sV [128 d][64 keys] | sP per-wave [32][72]
  // Q (128x128 = 32KB) staged once into sK+sV region before the loop.
  __shared__ bf16 smem[64 * 128 + 128 * 64 + 4 * 32 * 72];
  bf16* sK = smem;
  bf16* sV = smem + 64 * 128;
  bf16* sP = smem + 2 * 64 * 128;

  const int qb  = gridDim.x - 1 - blockIdx.x;  // heavy tiles dispatch first
  const int bh  = blockIdx.y;
  const int b   = bh >> 4;
  const int h   = bh & 15;
  const int tid = threadIdx.x;
  const int lane = tid & 63;
  const int w    = tid >> 6;
  const int quad = lane >> 4;
  const int l16  = lane & 15;

  const size_t rs = 6144;
  const bf16* Qg = qkv + (size_t)(b * 2048 + qb * 128) * rs + h * 128;
  const bf16* Kg = qkv + (size_t)(b * 2048) * rs + 2048 + h * 128;
  const bf16* Vg = Vt + (size_t)bh * 128 * 2048;

  // ---- stage Q (128x128) into smem, swizzled 16-chunk rows ----
#pragma unroll
  for (int s = 0; s < 8; ++s) {
    const int cid = (w * 8 + s) * 64 + lane;
    const int row = cid >> 4;
    const int col = ((cid & 15) ^ (row & 15)) << 3;
    async_load16(Qg + (size_t)row * rs + col, &smem[(w * 8 + s) * 64 * 8]);
  }
  __syncthreads();

  // Q fragments -> registers: subtile i (rows w*32+i*16+l16), kc 0..3
  bf16x8 qf[2][4];
#pragma unroll
  for (int i = 0; i < 2; ++i)
#pragma unroll
    for (int kc = 0; kc < 4; ++kc)
      qf[i][kc] = *(const bf16x8*)&smem[(w * 32 + i * 16 + l16) * 128 + (((kc * 4 + quad) ^ l16) << 3)];

  // K/V staging index precompute
  int qk_row[4], qk_col[4], v_row[4], v_col[4];
#pragma unroll
  for (int s = 0; s < 4; ++s) {
    const int cid = (w * 4 + s) * 64 + lane;
    qk_row[s] = cid >> 4;
    qk_col[s] = ((cid & 15) ^ (qk_row[s] & 15)) << 3;
    v_row[s]  = cid >> 3;
    v_col[s]  = ((cid & 7) ^ (v_row[s] & 7)) << 3;
  }

  floatx4 o[2][8];
#pragma unroll
  for (int i = 0; i < 2; ++i)
#pragma unroll
    for (int s = 0; s < 8; ++s) o[i][s] = (floatx4){0.f, 0.f, 0.f, 0.f};
  float m_i[2][4], l_i[2][4];
#pragma unroll
  for (int i = 0; i < 2; ++i)
#pragma unroll
    for (int r = 0; r < 4; ++r) { m_i[i][r] = -__builtin_inff(); l_i[i][r] = 0.f; }

  const float csc = 1.4426950408889634f * 0.08838834764831845f; // log2(e)/sqrt(128)
  const int kb_end = 2 * qb + 2;

  for (int kb = 0; kb < kb_end; ++kb) {
    __syncthreads();  // prev iter's frag reads done before overwrite
#pragma unroll
    for (int s = 0; s < 4; ++s) {
      async_load16(Kg + (size_t)(kb * 64 + qk_row[s]) * rs + qk_col[s], &sK[(w * 4 + s) * 64 * 8]);
      async_load16(Vg + (size_t)v_row[s] * 2048 + kb * 64 + v_col[s],   &sV[(w * 4 + s) * 64 * 8]);
    }
    __syncthreads();  // staging drained

    // wave-uniform skip: all keys of this tile above all of this wave's rows
    if (kb * 64 > qb * 128 + w * 32 + 31) continue;

    // S = Q_w(32x128) @ K^T(128x64): bk frags shared across the 2 m-subtiles
    floatx4 sacc[2][4];
#pragma unroll
    for (int i = 0; i < 2; ++i)
#pragma unroll
      for (int j = 0; j < 4; ++j) sacc[i][j] = (floatx4){0.f, 0.f, 0.f, 0.f};
#pragma unroll
    for (int kc = 0; kc < 4; ++kc) {
      const int ch = ((kc * 4 + quad) ^ l16) << 3;
#pragma unroll
      for (int j = 0; j < 4; ++j) {
        const bf16x8 bk = *(const bf16x8*)&sK[(j * 16 + l16) * 128 + ch];
        sacc[0][j] = MFMA_16x16x32(qf[0][kc], bk, sacc[0][j]);
        sacc[1][j] = MFMA_16x16x32(qf[1][kc], bk, sacc[1][j]);
      }
    }

    // scale + causal mask + online softmax (rows live in one 16-lane quad)
    const bool diag = (kb >= 2 * qb);  // only last two tiles touch the diagonal
    float p[2][4][4], mx[2][4];
    const int key0 = kb * 64 + l16;
#pragma unroll
    for (int i = 0; i < 2; ++i) {
      const int qrow = qb * 128 + w * 32 + i * 16 + quad * 4;
#pragma unroll
      for (int r = 0; r < 4; ++r) mx[i][r] = -__builtin_inff();
#pragma unroll
      for (int j = 0; j < 4; ++j)
#pragma unroll
        for (int r = 0; r < 4; ++r) {
          float v = sacc[i][j][r] * csc;
          if (diag && key0 + j * 16 > qrow + r) v = -__builtin_inff();
          p[i][j][r] = v;
          mx[i][r] = fmaxf(mx[i][r], v);
        }
    }
#pragma unroll
    for (int off = 1; off < 16; off <<= 1)
#pragma unroll
      for (int i = 0; i < 2; ++i)
#pragma unroll
        for (int r = 0; r < 4; ++r) mx[i][r] = fmaxf(mx[i][r], __shfl_xor(mx[i][r], off, 64));

    float rsum[2][4];
#pragma unroll
    for (int i = 0; i < 2; ++i)
#pragma unroll
      for (int r = 0; r < 4; ++r) {
        const float mnew = fmaxf(m_i[i][r], mx[i][r]);
        const float alpha = __builtin_amdgcn_exp2f(m_i[i][r] - mnew);
        m_i[i][r] = mnew;
        float rsl = 0.f;
#pragma unroll
        for (int j = 0; j < 4; ++j) {
          const float e = __builtin_amdgcn_exp2f(p[i][j][r] - mnew);
          p[i][j][r] = e;
          rsl += e;
        }
        rsum[i][r] = rsl;
        l_i[i][r] *= alpha;
#pragma unroll
        for (int s = 0; s < 8; ++s) o[i][s][r] *= alpha;
      }
#pragma unroll
    for (int off = 1; off < 16; off <<= 1)
#pragma unroll
      for (int i = 0; i < 2; ++i)
#pragma unroll
        for (int r = 0; r < 4; ++r) rsum[i][r] += __shfl_xor(rsum[i][r], off, 64);
#pragma unroll
    for (int i = 0; i < 2; ++i)
#pragma unroll
      for (int r = 0; r < 4; ++r) l_i[i][r] += rsum[i][r];

    // P: C-layout regs -> LDS (padded 72/row) -> A-layout frags (per-wave)
#pragma unroll
    for (int i = 0; i < 2; ++i)
#pragma unroll
      for (int j = 0; j < 4; ++j)
#pragma unroll
        for (int r = 0; r < 4; ++r)
          sP[w * 32 * 72 + (i * 16 + quad * 4 + r) * 72 + j * 16 + l16] = __float2bfloat16(p[i][j][r]);

    // O += P(32x64) @ V(64x128); bv frags shared across the 2 m-subtiles
#pragma unroll
    for (int kc = 0; kc < 2; ++kc) {
      const bf16x8 ap0 = *(const bf16x8*)&sP[w * 32 * 72 + (l16) * 72 + kc * 32 + quad * 8];
      const bf16x8 ap1 = *(const bf16x8*)&sP[w * 32 * 72 + (16 + l16) * 72 + kc * 32 + quad * 8];
      const int chv = ((kc * 4 + quad) ^ (l16 & 7)) << 3;
#pragma unroll
      for (int s = 0; s < 8; ++s) {
        const bf16x8 bv = *(const bf16x8*)&sV[(s * 16 + l16) * 64 + chv];
        o[0][s] = MFMA_16x16x32(ap0, bv, o[0][s]);
        o[1][s] = MFMA_16x16x32(ap1, bv, o[1][s]);
      }
    }
  }

  // epilogue: O /= l, write bf16 to [b*T + q, h*128 + dim]
#pragma unroll
  for (int i = 0; i < 2; ++i) {
    float rl[4];
#pragma unroll
    for (int r = 0; r < 4; ++r) rl[r] = 1.f / l_i[i][r];
    bf16* dst = outb + (size_t)(b * 2048 + qb * 128 + w * 32 + i * 16) * 2048 + h * 128;
#pragma unroll
    for (int s = 0; s < 8; ++s)
#pragma unroll
      for (int r = 0; r < 4; ++r)
        dst[(size_t)(quad * 4 + r) * 2048 + s * 16 + l16] = __float2bfloat16(o[i][s][r] * rl[r]);
  }
}

// ---------------------------------------------------------------------------
extern "C" void kernel_launch(void* const* d_in, const int* in_sizes, int n_in,
                              void* d_out, int out_size, void* d_ws, size_t ws_size,
                              hipStream_t stream)
{
  (void)in_sizes; (void)n_in; (void)out_size; (void)ws_size;
  const float* x  = (const float*)d_in[0];   // [4,2048,2048]
  const float* Wa = (const float*)d_in[1];   // [6144,2048]
  const float* Wp = (const float*)d_in[2];   // [2048,2048]
  float* out = (float*)d_out;                // [4,2048,2048] fp32
  char* ws = (char*)d_ws;

  bf16* xb   = (bf16*)(ws + 0);              //  33,554,432  x bf16 (dead after GEMM1)
  bf16* Wab  = (bf16*)(ws + 33554432ull);    //  25,165,824  W_attn bf16
  bf16* Wpb  = (bf16*)(ws + 58720256ull);    //   8,388,608  W_proj bf16
  bf16* qkv  = (bf16*)(ws + 67108864ull);    // 100,663,296  [8192,6144] bf16
  bf16* attb = (bf16*)(ws + 167772160ull);   //  33,554,432  attn out bf16
  bf16* Vt   = xb;                           // alias: V transposed [64][128][2048]

  f32_to_bf16_k<<<8192, 256, 0, stream>>>(x,  xb,  4 * 2048 * 2048);
  f32_to_bf16_k<<<6144, 256, 0, stream>>>(Wa, Wab, 3 * 2048 * 2048);
  f32_to_bf16_k<<<2048, 256, 0, stream>>>(Wp, Wpb, 2048 * 2048);

  // qkv = x @ W_attn^T   [8192,6144]
  gemm_bt<<<dim3(48, 64), 256, 0, stream>>>(xb, Wab, qkv, nullptr, 8192, 6144, 2048);
  // Vt[bh][d][t]
  transpose_v<<<dim3(32, 64), 256, 0, stream>>>(qkv, Vt);
  // attention: BQ=128 -> 16 q-tiles
  flash_attn<<<dim3(16, 64), 256, 0, stream>>>(qkv, Vt, attb);
  // out = attb @ W_proj^T  [8192,2048] fp32
  gemm_bt<<<dim3(16, 64), 256, 0, stream>>>(attb, Wpb, nullptr, out, 8192, 2048, 2048);
}

// Round 4
// 750.108 us; speedup vs baseline: 1.0357x; 1.0357x over previous
//
#include <hip/hip_runtime.h>
#include <hip/hip_bf16.h>
#include <stdint.h>

typedef __hip_bfloat16 bf16;
typedef __attribute__((ext_vector_type(8))) __bf16 bf16x8;
typedef __attribute__((ext_vector_type(8))) unsigned short ushort8;
typedef __attribute__((ext_vector_type(4))) float floatx4;

#define MFMA_16x16x32(a, b, c) __builtin_amdgcn_mfma_f32_16x16x32_bf16((a), (b), (c), 0, 0, 0)

// async global->LDS, 16B per lane. LDS dest = wave-uniform base + lane*16.
__device__ __forceinline__ void async_load16(const bf16* g, bf16* l) {
  __builtin_amdgcn_global_load_lds(
      (const __attribute__((address_space(1))) unsigned int*)g,
      (__attribute__((address_space(3))) unsigned int*)l,
      16, 0, 0);
}

// DPP cross-lane (VALU pipe, not LDS): 16-lane row reductions
template <int CTRL>
__device__ __forceinline__ float dpp_f(float x) {
  return __builtin_bit_cast(float, __builtin_amdgcn_update_dpp(
      0, __builtin_bit_cast(int, x), CTRL, 0xf, 0xf, true));
}
__device__ __forceinline__ float row_max16(float x) {
  x = fmaxf(x, dpp_f<0xB1>(x));   // quad_perm(1,0,3,2)
  x = fmaxf(x, dpp_f<0x4E>(x));   // quad_perm(2,3,0,1)
  x = fmaxf(x, dpp_f<0x124>(x));  // row_ror:4
  x = fmaxf(x, dpp_f<0x128>(x));  // row_ror:8
  return x;
}
__device__ __forceinline__ float row_sum16(float x) {
  x += dpp_f<0xB1>(x);
  x += dpp_f<0x4E>(x);
  x += dpp_f<0x124>(x);
  x += dpp_f<0x128>(x);
  return x;
}

// ---------------------------------------------------------------------------
// fp32 -> bf16 cast, 8 elems/thread
// ---------------------------------------------------------------------------
__global__ __launch_bounds__(256)
void f32_to_bf16_k(const float* __restrict__ in, bf16* __restrict__ out, int n)
{
  const int i = (blockIdx.x * 256 + threadIdx.x) * 8;
  if (i >= n) return;
  bf16 tmp[8];
#pragma unroll
  for (int j = 0; j < 8; ++j) tmp[j] = __float2bfloat16(in[i + j]);
  *(ushort8*)&out[i] = *(const ushort8*)tmp;
}

// ---------------------------------------------------------------------------
// C[M,N] = A[M,K] @ B[N,K]^T  — m97 tile + XOR swizzle + issue-after-barrier
// double-buffer: at __syncthreads the outstanding loads are one full compute
// phase old, so the vmcnt(0) drain is free. One barrier per K-step.
// ---------------------------------------------------------------------------
__global__ __launch_bounds__(256, 2)
void gemm_bt(const bf16* __restrict__ A, const bf16* __restrict__ B,
             bf16* __restrict__ Cb, float* __restrict__ Cf,
             int M, int N, int K)
{
  __shared__ __align__(16) bf16 sA[2][128 * 32];
  __shared__ __align__(16) bf16 sB[2][128 * 32];

  const int tid  = threadIdx.x;
  const int lane = tid & 63;
  const int w    = tid >> 6;
  const int wm   = w >> 1;
  const int wn   = w & 1;
  const int quad = lane >> 4;
  const int l16  = lane & 15;
  const int tileM = blockIdx.y * 128;
  const int tileN = blockIdx.x * 128;
  const int rmask = (l16 & 3) ^ ((l16 >> 2) & 3);

  floatx4 acc[4][4];
#pragma unroll
  for (int i = 0; i < 4; ++i)
#pragma unroll
    for (int j = 0; j < 4; ++j) acc[i][j] = (floatx4){0.f, 0.f, 0.f, 0.f};

  int st_row[2], st_col[2];
#pragma unroll
  for (int s = 0; s < 2; ++s) {
    const int cid = (w * 2 + s) * 64 + lane;
    const int row = cid >> 2;
    st_row[s] = row;
    st_col[s] = ((cid & 3) ^ ((row & 3) ^ ((row >> 2) & 3))) << 3;
  }

  // prologue: stage k0=0 into buf 0
#pragma unroll
  for (int s = 0; s < 2; ++s) {
    async_load16(A + (size_t)(tileM + st_row[s]) * K + st_col[s], &sA[0][(w * 2 + s) * 512]);
    async_load16(B + (size_t)(tileN + st_row[s]) * K + st_col[s], &sB[0][(w * 2 + s) * 512]);
  }

  int p = 0;
  for (int k0 = 0; k0 < K; k0 += 32, p ^= 1) {
    __syncthreads();  // drains loads(k0) (issued last iter) — latency hidden
    if (k0 + 32 < K) {
#pragma unroll
      for (int s = 0; s < 2; ++s) {
        async_load16(A + (size_t)(tileM + st_row[s]) * K + (k0 + 32) + st_col[s], &sA[p ^ 1][(w * 2 + s) * 512]);
        async_load16(B + (size_t)(tileN + st_row[s]) * K + (k0 + 32) + st_col[s], &sB[p ^ 1][(w * 2 + s) * 512]);
      }
    }

    bf16x8 af[4], bfr[4];
#pragma unroll
    for (int i = 0; i < 4; ++i)
      af[i] = *(const bf16x8*)&sA[p][(wm * 64 + i * 16 + l16) * 32 + (quad ^ rmask) * 8];
#pragma unroll
    for (int j = 0; j < 4; ++j)
      bfr[j] = *(const bf16x8*)&sB[p][(wn * 64 + j * 16 + l16) * 32 + (quad ^ rmask) * 8];
#pragma unroll
    for (int i = 0; i < 4; ++i)
#pragma unroll
      for (int j = 0; j < 4; ++j)
        acc[i][j] = MFMA_16x16x32(af[i], bfr[j], acc[i][j]);
  }

#pragma unroll
  for (int i = 0; i < 4; ++i)
#pragma unroll
    for (int j = 0; j < 4; ++j)
#pragma unroll
      for (int r = 0; r < 4; ++r) {
        const int row = tileM + wm * 64 + i * 16 + quad * 4 + r;
        const int col = tileN + wn * 64 + j * 16 + l16;
        if (Cf) Cf[(size_t)row * N + col] = acc[i][j][r];
        else    Cb[(size_t)row * N + col] = __float2bfloat16(acc[i][j][r]);
      }
}

// ---------------------------------------------------------------------------
// V transpose: qkv[b*T+t, 4096 + h*128 + dim] -> Vt[(bh*128 + dim)*2048 + t]
// ---------------------------------------------------------------------------
__global__ __launch_bounds__(256)
void transpose_v(const bf16* __restrict__ qkv, bf16* __restrict__ Vt)
{
  __shared__ bf16 tile[64 * 128];
  const int t0 = blockIdx.x * 64;
  const int bh = blockIdx.y;
  const int b = bh >> 4;
  const int h = bh & 15;
  const int tid = threadIdx.x;
  const bf16* src = qkv + (size_t)(b * 2048 + t0) * 6144 + 4096 + h * 128;
#pragma unroll
  for (int s = 0; s < 4; ++s) {
    const int cid = s * 256 + tid;
    const int row = cid >> 4;
    const int col = (cid & 15) << 3;
    *(ushort8*)&tile[row * 128 + col] = *(const ushort8*)&src[(size_t)row * 6144 + col];
  }
  __syncthreads();
  const int dim = tid >> 1;
  const int tp  = (tid & 1) << 5;
  bf16 vals[32];
#pragma unroll
  for (int t = 0; t < 32; ++t) vals[t] = tile[(tp + t) * 128 + dim];
  bf16* dst = Vt + (size_t)(bh * 128 + dim) * 2048 + t0 + tp;
#pragma unroll
  for (int s = 0; s < 4; ++s) *(ushort8*)&dst[s * 8] = ((const ushort8*)vals)[s];
}

// ---------------------------------------------------------------------------
// Flash attention, causal. BQ=128, BKV=32, double-buffered K/V, pipelined.
// 4 waves; wave w owns q-rows w*32..w*32+31 (2 m-subtiles). Q in registers.
// Softmax reductions via DPP (VALU pipe). LDS 42KB -> 3 blocks/CU.
// ---------------------------------------------------------------------------
__global__ __launch_bounds__(256, 2)
void flash_attn(const bf16* __restrict__ qkv, const bf16* __restrict__ Vt,
                bf16* __restrict__ outb)
{
  // buf p (8192 elems): sK [32 keys][128 d] at +0, sV [128 d][32 keys] at +4096
  // Q (128x128 = 16384 elems) staged once through both bufs. sP after.
  __shared__ __align__(16) bf16 smem[16384 + 4 * 32 * 40];
  bf16* sP = smem + 16384;

  const int qb  = gridDim.x - 1 - blockIdx.x;
  const int bh  = blockIdx.y;
  const int b   = bh >> 4;
  const int h   = bh & 15;
  const int tid = threadIdx.x;
  const int lane = tid & 63;
  const int w    = tid >> 6;
  const int quad = lane >> 4;
  const int l16  = lane & 15;

  const size_t rs = 6144;
  const bf16* Qg = qkv + (size_t)(b * 2048 + qb * 128) * rs + h * 128;
  const bf16* Kg = qkv + (size_t)(b * 2048) * rs + 2048 + h * 128;
  const bf16* Vg = Vt + (size_t)bh * 128 * 2048;

  // ---- stage Q (128x128), swizzled 16-chunk rows ----
#pragma unroll
  for (int s = 0; s < 8; ++s) {
    const int cid = (w * 8 + s) * 64 + lane;
    const int row = cid >> 4;
    const int col = ((cid & 15) ^ (row & 15)) << 3;
    async_load16(Qg + (size_t)row * rs + col, &smem[(w * 8 + s) * 512]);
  }
  __syncthreads();

  bf16x8 qf[2][4];
#pragma unroll
  for (int i = 0; i < 2; ++i)
#pragma unroll
    for (int kc = 0; kc < 4; ++kc)
      qf[i][kc] = *(const bf16x8*)&smem[(w * 32 + i * 16 + l16) * 128 + (((kc * 4 + quad) ^ l16) << 3)];
  __syncthreads();  // all waves done reading Q before buf0 is overwritten

  // K/V staging index precompute (2 insts each per wave per tile)
  int kq_row[2], kq_col[2], vv_row[2], vv_col[2];
#pragma unroll
  for (int s = 0; s < 2; ++s) {
    const int cid = (w * 2 + s) * 64 + lane;
    kq_row[s] = cid >> 4;                               // 16 chunks per 128-d row
    kq_col[s] = ((cid & 15) ^ (kq_row[s] & 15)) << 3;
    vv_row[s] = cid >> 2;                               // 4 chunks per 32-key row
    vv_col[s] = ((cid & 3) ^ (vv_row[s] & 3)) << 3;
  }

  const int kb_end = 4 * qb + 4;
  // prologue: stage tile 0 into buf 0
#pragma unroll
  for (int s = 0; s < 2; ++s) {
    async_load16(Kg + (size_t)kq_row[s] * rs + kq_col[s],      &smem[(w * 2 + s) * 512]);
    async_load16(Vg + (size_t)vv_row[s] * 2048 + vv_col[s],    &smem[4096 + (w * 2 + s) * 512]);
  }

  floatx4 o[2][8];
#pragma unroll
  for (int i = 0; i < 2; ++i)
#pragma unroll
    for (int s = 0; s < 8; ++s) o[i][s] = (floatx4){0.f, 0.f, 0.f, 0.f};
  float m_i[2][4], l_i[2][4];
#pragma unroll
  for (int i = 0; i < 2; ++i)
#pragma unroll
    for (int r = 0; r < 4; ++r) { m_i[i][r] = -__builtin_inff(); l_i[i][r] = 0.f; }

  const float csc = 1.4426950408889634f * 0.08838834764831845f; // log2(e)/sqrt(128)

  for (int kb = 0; kb < kb_end; ++kb) {
    __syncthreads();  // drains loads(kb) (issued last iter) + protects bufs
    if (kb + 1 < kb_end) {
      bf16* nb = smem + ((kb + 1) & 1) * 8192;
#pragma unroll
      for (int s = 0; s < 2; ++s) {
        async_load16(Kg + (size_t)((kb + 1) * 32 + kq_row[s]) * rs + kq_col[s], nb + (w * 2 + s) * 512);
        async_load16(Vg + (size_t)vv_row[s] * 2048 + (kb + 1) * 32 + vv_col[s], nb + 4096 + (w * 2 + s) * 512);
      }
    }
    // wave-uniform skip: whole key tile above all of this wave's rows
    if (kb * 32 > qb * 128 + w * 32 + 31) continue;

    const bf16* sK = smem + (kb & 1) * 8192;
    const bf16* sV = sK + 4096;

    // S = Q_w(32x128) @ K^T(128x32)
    floatx4 sacc[2][2];
#pragma unroll
    for (int i = 0; i < 2; ++i)
#pragma unroll
      for (int j = 0; j < 2; ++j) sacc[i][j] = (floatx4){0.f, 0.f, 0.f, 0.f};
#pragma unroll
    for (int kc = 0; kc < 4; ++kc) {
      const int ch = ((kc * 4 + quad) ^ l16) << 3;
#pragma unroll
      for (int j = 0; j < 2; ++j) {
        const bf16x8 bk = *(const bf16x8*)&sK[(j * 16 + l16) * 128 + ch];
        sacc[0][j] = MFMA_16x16x32(qf[0][kc], bk, sacc[0][j]);
        sacc[1][j] = MFMA_16x16x32(qf[1][kc], bk, sacc[1][j]);
      }
    }

    // scale + causal mask + online softmax (row = 16 contiguous lanes)
    const bool diag = (kb * 32 + 31 > qb * 128 + w * 32);
    float p[2][2][4];
#pragma unroll
    for (int i = 0; i < 2; ++i) {
      const int qrow = qb * 128 + w * 32 + i * 16 + quad * 4;
#pragma unroll
      for (int r = 0; r < 4; ++r) {
        float mx = -__builtin_inff();
#pragma unroll
        for (int j = 0; j < 2; ++j) {
          float v = sacc[i][j][r] * csc;
          if (diag && kb * 32 + j * 16 + l16 > qrow + r) v = -__builtin_inff();
          p[i][j][r] = v;
          mx = fmaxf(mx, v);
        }
        mx = row_max16(mx);
        const float mnew = fmaxf(m_i[i][r], mx);
        const float alpha = __builtin_amdgcn_exp2f(m_i[i][r] - mnew);
        m_i[i][r] = mnew;
        float rsl = 0.f;
#pragma unroll
        for (int j = 0; j < 2; ++j) {
          const float e = __builtin_amdgcn_exp2f(p[i][j][r] - mnew);
          p[i][j][r] = e;
          rsl += e;
        }
        l_i[i][r] = alpha * l_i[i][r] + row_sum16(rsl);
#pragma unroll
        for (int s = 0; s < 8; ++s) o[i][s][r] *= alpha;
      }
    }

    // P: C-layout regs -> LDS (pad 40, 16B-aligned rows) -> A-layout frags
#pragma unroll
    for (int i = 0; i < 2; ++i)
#pragma unroll
      for (int j = 0; j < 2; ++j)
#pragma unroll
        for (int r = 0; r < 4; ++r)
          sP[w * 1280 + (i * 16 + quad * 4 + r) * 40 + j * 16 + l16] = __float2bfloat16(p[i][j][r]);

    // O += P(32x32) @ V(32x128): single K-step (BKV=32)
    const bf16x8 ap0 = *(const bf16x8*)&sP[w * 1280 + l16 * 40 + quad * 8];
    const bf16x8 ap1 = *(const bf16x8*)&sP[w * 1280 + (16 + l16) * 40 + quad * 8];
    const int chv = (quad ^ (l16 & 3)) << 3;
#pragma unroll
    for (int s = 0; s < 8; ++s) {
      const bf16x8 bv = *(const bf16x8*)&sV[(s * 16 + l16) * 32 + chv];
      o[0][s] = MFMA_16x16x32(ap0, bv, o[0][s]);
      o[1][s] = MFMA_16x16x32(ap1, bv, o[1][s]);
    }
  }

  // epilogue: O /= l, write bf16
#pragma unroll
  for (int i = 0; i < 2; ++i) {
    float rl[4];
#pragma unroll
    for (int r = 0; r < 4; ++r) rl[r] = 1.f / l_i[i][r];
    bf16* dst = outb + (size_t)(b * 2048 + qb * 128 + w * 32 + i * 16) * 2048 + h * 128;
#pragma unroll
    for (int s = 0; s < 8; ++s)
#pragma unroll
      for (int r = 0; r < 4; ++r)
        dst[(size_t)(quad * 4 + r) * 2048 + s * 16 + l16] = __float2bfloat16(o[i][s][r] * rl[r]);
  }
}

// ---------------------------------------------------------------------------
extern "C" void kernel_launch(void* const* d_in, const int* in_sizes, int n_in,
                              void* d_out, int out_size, void* d_ws, size_t ws_size,
                              hipStream_t stream)
{
  (void)in_sizes; (void)n_in; (void)out_size; (void)ws_size;
  const float* x  = (const float*)d_in[0];   // [4,2048,2048]
  const float* Wa = (const float*)d_in[1];   // [6144,2048]
  const float* Wp = (const float*)d_in[2];   // [2048,2048]
  float* out = (float*)d_out;                // [4,2048,2048] fp32
  char* ws = (char*)d_ws;

  bf16* xb   = (bf16*)(ws + 0);              //  33,554,432  x bf16 (dead after GEMM1)
  bf16* Wab  = (bf16*)(ws + 33554432ull);    //  25,165,824  W_attn bf16
  bf16* Wpb  = (bf16*)(ws + 58720256ull);    //   8,388,608  W_proj bf16
  bf16* qkv  = (bf16*)(ws + 67108864ull);    // 100,663,296  [8192,6144] bf16
  bf16* attb = (bf16*)(ws + 167772160ull);   //  33,554,432  attn out bf16
  bf16* Vt   = xb;                           // alias: V transposed [64][128][2048]

  f32_to_bf16_k<<<8192, 256, 0, stream>>>(x,  xb,  4 * 2048 * 2048);
  f32_to_bf16_k<<<6144, 256, 0, stream>>>(Wa, Wab, 3 * 2048 * 2048);
  f32_to_bf16_k<<<2048, 256, 0, stream>>>(Wp, Wpb, 2048 * 2048);

  // qkv = x @ W_attn^T   [8192,6144]
  gemm_bt<<<dim3(48, 64), 256, 0, stream>>>(xb, Wab, qkv, nullptr, 8192, 6144, 2048);
  // Vt[bh][d][t]
  transpose_v<<<dim3(32, 64), 256, 0, stream>>>(qkv, Vt);
  // attention: BQ=128 -> 16 q-tiles
  flash_attn<<<dim3(16, 64), 256, 0, stream>>>(qkv, Vt, attb);
  // out = attb @ W_proj^T  [8192,2048] fp32
  gemm_bt<<<dim3(16, 64), 256, 0, stream>>>(attb, Wpb, nullptr, out, 8192, 2048, 2048);
}